// Round 6
// baseline (133.095 us; speedup 1.0000x reference)
//
#include <hip/hip_runtime.h>
#include <math.h>

// HierarchicalPooling collapsed pipeline, round 6.
// N=32768, D=256, S=4, H=8, DH=32, CS=3276, C=11.
// R5 lessons: kbd2 latency-bound (VALU 21%, occ 17%, conflicts 0) — too few
// waves, too many syncs, 32x redundant pass-1 LDS reads.
// R6: 512-thr blocks (8 waves), no-max softmax (scores bounded ~1.5 so exp()
// is safe; ratio identical to ref), strided d-slices for conflict-free
// pass-1 reads, 32-node subtiles staged once, kp+ko fused.

namespace {
constexpr int N   = 32768;
constexpr int D   = 256;
constexpr int CS  = 3276;
constexpr int CPN = 64;                // nodes per kbd3 block
constexpr int CPC = 52;                // 64-node chunks per full cluster
constexpr int NB  = CPC*10 + 1;        // 521 blocks

// ws layout (float offsets); total ~17.7 MB
constexpr size_t WQ_OFF  = 0;                                // 32*256
constexpr size_t CQ_OFF  = WQ_OFF + 8192;                    // 32
constexpr size_t PART_OFF= CQ_OFF + 32;                      // NB*8192 chunk xw partials (unnormalized)
constexpr size_t PS_OFF  = PART_OFF + (size_t)NB*8192;       // NB*32 chunk sum-exp
constexpr size_t XW_OFF  = PS_OFF + (size_t)NB*32;           // 11*8192 normalized xw
constexpr size_t OL_OFF  = XW_OFF + 11*8192;                 // 11*1024 out rows
constexpr size_t HP_OFF  = OL_OFF + 11264;                   // 11*4*256 Wf1 partials
constexpr size_t HL_OFF  = HP_OFF + 11264;                   // 11*256 gelu(h)
constexpr size_t FP_OFF  = HL_OFF + 2816;                    // 11*4*256 Wf2 partials
}

// ---- KA: wq[sh][d] = scale * <Wk[s][d][h*32..], q[s][h]>, cq[sh] from bk.
__global__ __launch_bounds__(256) void ka(const float* __restrict__ Wk, const float* __restrict__ bk,
                                          const float* __restrict__ pq, float* __restrict__ ws){
  int b = blockIdx.x, t = threadIdx.x;
  const float scale = 0.17677669529663688f;   // 32^-0.5
  if (b < 32){
    int s = b >> 3, h = b & 7;
    const float* wrow = Wk + ((size_t)s<<16) + (size_t)t*256 + h*32;
    const float* q = pq + (s*8 + h)*32;
    float a = 0.f;
#pragma unroll
    for (int j=0;j<32;j++) a = fmaf(wrow[j], q[j], a);
    ws[WQ_OFF + (size_t)b*256 + t] = a*scale;
  } else if (t < 32){
    int s = t >> 3, h = t & 7;
    const float* br = bk + s*256 + h*32;
    const float* q = pq + t*32;
    float a = 0.f;
#pragma unroll
    for (int j=0;j<32;j++) a = fmaf(br[j], q[j], a);
    ws[CQ_OFF + t] = a*scale;
  }
}

// ---- KBD3: fused scores + exp + chunk sums + chunk xw partials. 521 blocks x 512.
// Pass-1 thread role: sh = t>>4 (0..31), dg = t&15 (lane bits 0-3, shfl-reducible).
//   dg owns strided d-slice {q*64 + dg*4 + e} -> LDS banks (4dg+e)%32, 2-way = free.
// Pass-2 thread role: d = t&255, sg = t>>8; acc[16] over sh = sg*16..+15.
__global__ __launch_bounds__(512,4) void kbd3(const float* __restrict__ x, float* __restrict__ ws){
  int b = blockIdx.x, t = threadIdx.x;
  int c  = (b < 520) ? (b / CPC) : 10;
  int wi = (b < 520) ? (b % CPC) : 0;
  int n0 = c*CS + wi*CPN;
  int n1 = min(n0 + CPN, min((c+1)*CS, N));
  int cnt = n1 - n0;                    // 64, 12 (cluster tails), or 8 (cluster 10)

  __shared__ float xt[32*256];          // 32 KB subtile
  __shared__ float sw[32*32];           // exp-weights [j][sh]

  int sh = t >> 4, dg = t & 15;
  const float4* WQ4 = (const float4*)(ws + WQ_OFF);
  float4 wqr[4];
#pragma unroll
  for (int q=0;q<4;q++) wqr[q] = WQ4[sh*64 + q*16 + dg];   // strided slice matches read pattern
  float cqr = ws[CQ_OFF + sh];
  const float4* X4 = (const float4*)x;

  int d = t & 255, sg = t >> 8;
  float acc[16];
#pragma unroll
  for (int q=0;q<16;q++) acc[q] = 0.f;
  float psr = 0.f;                      // sum-exp accumulator (threads t<32)

  int nst = (cnt + 31) >> 5;
  for (int st=0; st<nst; ++st){
    int nb = n0 + st*32;
    int cst = min(32, n1 - nb);
    __syncthreads();                    // xt/sw reuse
    // stage 32 nodes, coalesced float4 (pad rows zeroed)
#pragma unroll
    for (int k=0;k<4;k++){
      int f = t + k*512;
      int j = f >> 6, c4 = f & 63;
      float4 v = (j < cst) ? X4[(size_t)(nb+j)*64 + c4] : make_float4(0.f,0.f,0.f,0.f);
      *(float4*)(xt + j*256 + c4*4) = v;
    }
    __syncthreads();
    // pass 1: scores -> exp-weights (in-wave shfl reduce over dg)
#pragma unroll 8
    for (int j=0;j<cst;++j){
      const float4* xr = (const float4*)(xt + j*256);
      float a = 0.f;
#pragma unroll
      for (int q=0;q<4;q++){
        float4 xv = xr[q*16 + dg];
        a = fmaf(xv.x, wqr[q].x, a); a = fmaf(xv.y, wqr[q].y, a);
        a = fmaf(xv.z, wqr[q].z, a); a = fmaf(xv.w, wqr[q].w, a);
      }
      a += __shfl_xor(a, 1, 64);
      a += __shfl_xor(a, 2, 64);
      a += __shfl_xor(a, 4, 64);
      a += __shfl_xor(a, 8, 64);
      if (dg == 0) sw[j*32 + sh] = __expf(a + cqr);
    }
    __syncthreads();                    // sw ready
    // chunk sum-exp partial (threads t<32, read-only on sw)
    if (t < 32){
      for (int j=0;j<cst;++j) psr += sw[j*32 + t];
    }
    // pass 2: unnormalized xw accumulation
#pragma unroll 4
    for (int j=0;j<cst;++j){
      float xv = xt[j*256 + d];
      const float4* W4 = (const float4*)(sw + j*32 + sg*16);
#pragma unroll
      for (int q=0;q<4;q++){
        float4 w = W4[q];
        acc[4*q  ] = fmaf(w.x, xv, acc[4*q  ]);
        acc[4*q+1] = fmaf(w.y, xv, acc[4*q+1]);
        acc[4*q+2] = fmaf(w.z, xv, acc[4*q+2]);
        acc[4*q+3] = fmaf(w.w, xv, acc[4*q+3]);
      }
    }
  }
  if (t < 32) ws[PS_OFF + (size_t)b*32 + t] = psr;
  float* pr = ws + PART_OFF + (size_t)b*8192;
#pragma unroll
  for (int q=0;q<16;q++) pr[(size_t)(sg*16 + q)*256 + d] = acc[q];
}

// ---- KE2: sum chunk partials / denom -> xw[c][sh][d]. 352 blocks (one per (c,sh)).
__global__ __launch_bounds__(256) void ke2(float* __restrict__ ws){
  int b = blockIdx.x, t = threadIdx.x;
  int c = b >> 5, sh = b & 31;
  int nch = (c < 10) ? CPC : 1;
  int cb  = (c < 10) ? c*CPC : 520;
  const float* ps = ws + PS_OFF;
  float S = 0.f;
  for (int k=0;k<nch;k++) S += ps[(size_t)(cb+k)*32 + sh];
  float rden = 1.0f / S;
  const float* part = ws + PART_OFF + (size_t)sh*256 + t;
  float a = 0.f;
  for (int k=0;k<nch;k++) a += part[(size_t)(cb+k)*8192];
  ws[XW_OFF + (size_t)c*8192 + (size_t)sh*256 + t] = a * rden;
}

// ---- KPO: fused pooled -> out per (c,s). 44 blocks x 256.
__global__ __launch_bounds__(256) void kpo(float* __restrict__ ws,
    const float* __restrict__ Wv, const float* __restrict__ bv,
    const float* __restrict__ Wo, const float* __restrict__ bo){
  int b = blockIdx.x; int c = b >> 2, s = b & 3; int t = threadIdx.x;
  __shared__ float xwl[8*256];          // 8 heads x 256 d
  __shared__ float pl[256];
  const float* xwc = ws + XW_OFF + (size_t)c*8192 + (size_t)s*2048;
#pragma unroll
  for (int k=0;k<8;k++) xwl[k*256 + t] = xwc[k*256 + t];
  __syncthreads();
  float rcnt = (c < 10) ? (1.0f/(float)CS) : 0.125f;
  int h = t >> 5;
  {
    float a = 0.f;
    const float* wv = Wv + (size_t)s*65536 + t;
    const float* xr = xwl + h*256;
#pragma unroll 8
    for (int dd=0; dd<256; ++dd) a = fmaf(wv[(size_t)dd*256], xr[dd], a);
    pl[t] = (a + bv[s*256 + t]) * rcnt;
  }
  __syncthreads();
  {
    float o = 0.f;
    const float* wo = Wo + (size_t)s*65536 + t;
#pragma unroll 8
    for (int dd=0; dd<256; ++dd) o = fmaf(wo[(size_t)dd*256], pl[dd], o);
    ws[OL_OFF + (size_t)c*1024 + s*256 + t] = o + bo[s*256 + t];
  }
}

// ---- KF1: h partials: block (c, fq, kq), f-slice 64, k-slice 256. 176 blocks.
__global__ __launch_bounds__(256) void kf1(const float* __restrict__ Wf1, float* __restrict__ ws){
  int b = blockIdx.x; int c = b >> 4, fq = (b >> 2) & 3, kq = b & 3;
  int t = threadIdx.x, f64 = t & 63, ks = t >> 6;
  const float* ol = ws + OL_OFF + (size_t)c*1024 + kq*256 + ks*64;
  const float* wf = Wf1 + (size_t)(kq*256 + ks*64)*256 + fq*64 + f64;
  float a = 0.f;
#pragma unroll 8
  for (int i=0; i<64; ++i) a = fmaf(wf[(size_t)i*256], ol[i], a);
  __shared__ float red[4][64];
  red[ks][f64] = a;
  __syncthreads();
  if (t < 64)
    ws[HP_OFF + (size_t)(c*4 + kq)*256 + fq*64 + t] = red[0][t]+red[1][t]+red[2][t]+red[3][t];
}

// ---- KLN: combine partials + bias -> LayerNorm -> GELU. 11 blocks.
__global__ __launch_bounds__(256) void kln(float* __restrict__ ws, const float* __restrict__ bf1,
    const float* __restrict__ lng, const float* __restrict__ lnb){
  int c = blockIdx.x, t = threadIdx.x;
  __shared__ float rs1[4], rs2[4];
  float hacc = bf1[t];
#pragma unroll
  for (int q=0;q<4;q++) hacc += ws[HP_OFF + (size_t)(c*4+q)*256 + t];
  float s1 = hacc, s2v = hacc*hacc;
  for (int off=32; off>0; off>>=1){ s1 += __shfl_down(s1, off, 64); s2v += __shfl_down(s2v, off, 64); }
  int wid = t>>6, lane = t&63;
  if (lane==0){ rs1[wid]=s1; rs2[wid]=s2v; }
  __syncthreads();
  float S1 = rs1[0]+rs1[1]+rs1[2]+rs1[3];
  float S2 = rs2[0]+rs2[1]+rs2[2]+rs2[3];
  float mu = S1*(1.0f/256.0f);
  float var = S2*(1.0f/256.0f) - mu*mu;
  float rsig = rsqrtf(var + 1e-5f);
  float hn = (hacc - mu)*rsig*lng[t] + lnb[t];
  float ge = 0.5f*hn*(1.0f + erff(hn*0.70710678118654752f));   // exact GELU
  ws[HL_OFF + (size_t)c*256 + t] = ge;
}

// ---- KF2: f2 partials: block (c, gq, kq), g-slice 64, k-slice 64. 176 blocks.
__global__ __launch_bounds__(256) void kf2(const float* __restrict__ Wf2, float* __restrict__ ws){
  int b = blockIdx.x; int c = b >> 4, gq = (b >> 2) & 3, kq = b & 3;
  int t = threadIdx.x, g64 = t & 63, ks = t >> 6;
  const float* hp = ws + HL_OFF + (size_t)c*256 + kq*64 + ks*16;
  const float* wf = Wf2 + (size_t)(kq*64 + ks*16)*256 + gq*64 + g64;
  float a = 0.f;
#pragma unroll
  for (int i=0; i<16; ++i) a = fmaf(wf[(size_t)i*256], hp[i], a);
  __shared__ float red[4][64];
  red[ks][g64] = a;
  __syncthreads();
  if (t < 64)
    ws[FP_OFF + (size_t)(c*4 + kq)*256 + gq*64 + t] = red[0][t]+red[1][t]+red[2][t]+red[3][t];
}

// ---- KBC2: sum Wf2 partials + bf2 once per block, broadcast to nodes. 8192 blocks.
__global__ __launch_bounds__(256) void kbc2(const float* __restrict__ ws, float4* __restrict__ out,
                                            const float* __restrict__ bf2){
  unsigned bidx = blockIdx.x, t = threadIdx.x;
  unsigned idx = bidx*256u + t;
  unsigned c = (bidx*4u) / (unsigned)CS;   // 3276 % 4 == 0 -> one cluster per block
  __shared__ float4 row[64];
  if (t < 64){
    const float4* FP4 = (const float4*)(ws + FP_OFF);
    float4 s0 = FP4[(c*4+0)*64 + t];
    float4 s1 = FP4[(c*4+1)*64 + t];
    float4 s2 = FP4[(c*4+2)*64 + t];
    float4 s3 = FP4[(c*4+3)*64 + t];
    float4 bb = ((const float4*)bf2)[t];
    row[t] = make_float4(s0.x+s1.x+s2.x+s3.x+bb.x, s0.y+s1.y+s2.y+s3.y+bb.y,
                         s0.z+s1.z+s2.z+s3.z+bb.z, s0.w+s1.w+s2.w+s3.w+bb.w);
  }
  __syncthreads();
  out[idx] = row[t & 63u];
}

extern "C" void kernel_launch(void* const* d_in, const int* in_sizes, int n_in,
                              void* d_out, int out_size, void* d_ws, size_t ws_size,
                              hipStream_t stream) {
  const float* x   = (const float*)d_in[0];
  // d_in[1] edge_index, d_in[2] batch: unused by the reference computation
  const float* Wk  = (const float*)d_in[3];
  const float* bk  = (const float*)d_in[4];
  const float* Wv  = (const float*)d_in[5];
  const float* bv  = (const float*)d_in[6];
  const float* Wo  = (const float*)d_in[7];
  const float* bo  = (const float*)d_in[8];
  const float* pq  = (const float*)d_in[9];
  const float* Wf1 = (const float*)d_in[10];
  const float* bf1 = (const float*)d_in[11];
  const float* lng = (const float*)d_in[12];
  const float* lnb = (const float*)d_in[13];
  const float* Wf2 = (const float*)d_in[14];
  const float* bf2 = (const float*)d_in[15];
  float* ws = (float*)d_ws;
  float4* out = (float4*)d_out;

  hipLaunchKernelGGL(ka,   dim3(33),   dim3(256), 0, stream, Wk, bk, pq, ws);
  hipLaunchKernelGGL(kbd3, dim3(NB),   dim3(512), 0, stream, x, ws);
  hipLaunchKernelGGL(ke2,  dim3(352),  dim3(256), 0, stream, ws);
  hipLaunchKernelGGL(kpo,  dim3(44),   dim3(256), 0, stream, ws, Wv, bv, Wo, bo);
  hipLaunchKernelGGL(kf1,  dim3(176),  dim3(256), 0, stream, Wf1, ws);
  hipLaunchKernelGGL(kln,  dim3(11),   dim3(256), 0, stream, ws, bf1, lng, lnb);
  hipLaunchKernelGGL(kf2,  dim3(176),  dim3(256), 0, stream, Wf2, ws);
  hipLaunchKernelGGL(kbc2, dim3(8192), dim3(256), 0, stream, ws, out, bf2);
}

// Round 7
// 93.478 us; speedup vs baseline: 1.4238x; 1.4238x over previous
//
#include <hip/hip_runtime.h>
#include <math.h>

// HierarchicalPooling collapsed pipeline, round 7.
// N=32768, D=256, S=4, H=8, DH=32, CS=3276, C=11.
// R6 lesson: kbd3 was LDS-instruction-pipe bound (~6.6K DS wave-insts/block:
// shfl_xor lowers to ds_bpermute, pass-2 issued 5 DS/j/wave). R7: DPP rotate
// reduction (pure VALU), tiled pass-2 (3 DS/j/wave), 64-node tile staged once,
// 2 barriers/block, exp+denominator folded into pass 1 with PS atomics.
// Middle chain reverted to R5's measured shapes (kpo fusion regressed +25us).

namespace {
constexpr int N   = 32768;
constexpr int D   = 256;
constexpr int CS  = 3276;
constexpr int CPC = 52;                // 64-node chunks per full cluster
constexpr int NB  = CPC*10 + 1;        // 521 blocks

// ws layout (float offsets); total ~17.7 MB
constexpr size_t WQ_OFF  = 0;                                // 32*256
constexpr size_t CQ_OFF  = WQ_OFF + 8192;                    // 32
constexpr size_t PART_OFF= CQ_OFF + 32;                      // NB*8192 chunk xw partials
constexpr size_t PS_OFF  = PART_OFF + (size_t)NB*8192;       // 11*32 cluster sum-exp (atomic)
constexpr size_t XW_OFF  = PS_OFF + 352;                     // 11*8192 normalized xw
constexpr size_t PL_OFF  = XW_OFF + 90112;                   // 11*1024 pooled
constexpr size_t OL_OFF  = PL_OFF + 11264;                   // 11*1024 out rows
constexpr size_t HP_OFF  = OL_OFF + 11264;                   // 11*4*256 Wf1 partials
constexpr size_t HL_OFF  = HP_OFF + 11264;                   // 11*256 gelu(h)
constexpr size_t FP_OFF  = HL_OFF + 2816;                    // 11*4*256 Wf2 partials
}

// DPP sum over each 16-lane row: xor1 (quad_perm), xor2 (quad_perm), ror4, ror8.
__device__ __forceinline__ float dpp_red16(float a){
  int x;
  x = __builtin_amdgcn_update_dpp(0, __float_as_int(a), 0xB1,  0xf, 0xf, true); a += __int_as_float(x);
  x = __builtin_amdgcn_update_dpp(0, __float_as_int(a), 0x4E,  0xf, 0xf, true); a += __int_as_float(x);
  x = __builtin_amdgcn_update_dpp(0, __float_as_int(a), 0x124, 0xf, 0xf, true); a += __int_as_float(x);
  x = __builtin_amdgcn_update_dpp(0, __float_as_int(a), 0x128, 0xf, 0xf, true); a += __int_as_float(x);
  return a;
}

// ---- KA: wq[sh][d] = scale * <Wk[s][d][h*32..], q[s][h]>, cq[sh] from bk.
__global__ __launch_bounds__(256) void ka(const float* __restrict__ Wk, const float* __restrict__ bk,
                                          const float* __restrict__ pq, float* __restrict__ ws){
  int b = blockIdx.x, t = threadIdx.x;
  const float scale = 0.17677669529663688f;   // 32^-0.5
  if (b < 32){
    int s = b >> 3, h = b & 7;
    const float* wrow = Wk + ((size_t)s<<16) + (size_t)t*256 + h*32;
    const float* q = pq + (s*8 + h)*32;
    float a = 0.f;
#pragma unroll
    for (int j=0;j<32;j++) a = fmaf(wrow[j], q[j], a);
    ws[WQ_OFF + (size_t)b*256 + t] = a*scale;
  } else if (t < 32){
    int s = t >> 3, h = t & 7;
    const float* br = bk + s*256 + h*32;
    const float* q = pq + t*32;
    float a = 0.f;
#pragma unroll
    for (int j=0;j<32;j++) a = fmaf(br[j], q[j], a);
    ws[CQ_OFF + t] = a*scale;
  }
}

// ---- KBD4: fused scores + exp + PS atomics + xw chunk partials.
// 521 blocks x 512 threads; 64-node tile staged once; 2 barriers.
// Pass 1: sh = t>>4, dg = t&15 (strided float4 slice q*16+dg, conflict-free);
//   DPP-reduce over the 16-lane row; dg==0 lane exps/stores/psums.
// Pass 2: shq = t>>6 (4 sh), dq = t&63 (4 d); per j: 1 contiguous b128 (xt)
//   + 1 broadcast b128 (sw) + 16 FMA; coalesced float4 partial stores.
__global__ __launch_bounds__(512,4) void kbd4(const float* __restrict__ x, float* __restrict__ ws){
  int b = blockIdx.x, t = threadIdx.x;
  int c  = (b < 520) ? (b / CPC) : 10;
  int wi = (b < 520) ? (b % CPC) : 0;
  int n0 = c*CS + wi*64;
  int n1 = min(n0 + 64, min((c+1)*CS, N));
  int cnt = n1 - n0;                    // 64, 12 (cluster tails), or 8 (cluster 10)

  __shared__ float xt[64*256];          // 64 KB tile
  __shared__ float sw[64*36];           // exp-weights, stride 36 (16B-aligned)

  const float4* X4 = (const float4*)x;
  int rows_avail = N - n0;
#pragma unroll
  for (int k=0;k<8;k++){
    int f = t + k*512;
    int j = f >> 6, c4 = f & 63;
    if (j < rows_avail)                 // guard OOB for the 2 tail blocks
      *(float4*)(xt + j*256 + c4*4) = X4[(size_t)(n0+j)*64 + c4];
  }

  int sh = t >> 4, dg = t & 15;
  const float4* WQ4 = (const float4*)(ws + WQ_OFF);
  float4 wqr[4];
#pragma unroll
  for (int q=0;q<4;q++) wqr[q] = WQ4[sh*64 + q*16 + dg];   // strided slice
  float cqr = ws[CQ_OFF + sh];

  __syncthreads();

  // ---- pass 1: scores -> exp-weights + per-(c,sh) sum
  float psum = 0.f;
#pragma unroll 4
  for (int j=0;j<cnt;++j){
    const float4* xr = (const float4*)(xt + j*256);
    float a = 0.f;
#pragma unroll
    for (int q=0;q<4;q++){
      float4 xv = xr[q*16 + dg];
      a = fmaf(xv.x, wqr[q].x, a); a = fmaf(xv.y, wqr[q].y, a);
      a = fmaf(xv.z, wqr[q].z, a); a = fmaf(xv.w, wqr[q].w, a);
    }
    a = dpp_red16(a);
    if (dg == 0){
      float e = __expf(a + cqr);        // scores bounded ~1.5; no max needed (R6-validated)
      sw[j*36 + sh] = e;
      psum += e;
    }
  }
  if (dg == 0) unsafeAtomicAdd(ws + PS_OFF + (size_t)c*32 + sh, psum);
  __syncthreads();

  // ---- pass 2: xw chunk partials, 4sh x 4d tile per thread
  int shq = t >> 6, dq = t & 63;
  float acc[16];
#pragma unroll
  for (int q=0;q<16;q++) acc[q] = 0.f;
#pragma unroll 4
  for (int j=0;j<cnt;++j){
    float4 xv = *(const float4*)(xt + j*256 + dq*4);
    float4 wv = *(const float4*)(sw + j*36 + shq*4);
    acc[0]  = fmaf(wv.x, xv.x, acc[0]);  acc[1]  = fmaf(wv.x, xv.y, acc[1]);
    acc[2]  = fmaf(wv.x, xv.z, acc[2]);  acc[3]  = fmaf(wv.x, xv.w, acc[3]);
    acc[4]  = fmaf(wv.y, xv.x, acc[4]);  acc[5]  = fmaf(wv.y, xv.y, acc[5]);
    acc[6]  = fmaf(wv.y, xv.z, acc[6]);  acc[7]  = fmaf(wv.y, xv.w, acc[7]);
    acc[8]  = fmaf(wv.z, xv.x, acc[8]);  acc[9]  = fmaf(wv.z, xv.y, acc[9]);
    acc[10] = fmaf(wv.z, xv.z, acc[10]); acc[11] = fmaf(wv.z, xv.w, acc[11]);
    acc[12] = fmaf(wv.w, xv.x, acc[12]); acc[13] = fmaf(wv.w, xv.y, acc[13]);
    acc[14] = fmaf(wv.w, xv.z, acc[14]); acc[15] = fmaf(wv.w, xv.w, acc[15]);
  }
  float* pr = ws + PART_OFF + (size_t)b*8192;
#pragma unroll
  for (int i=0;i<4;i++)
    *(float4*)(pr + (size_t)(shq*4+i)*256 + dq*4) = make_float4(acc[i*4], acc[i*4+1], acc[i*4+2], acc[i*4+3]);
}

// ---- KE2: sum chunk partials / PS -> xw[c][sh][d]. 352 blocks (one per (c,sh)).
__global__ __launch_bounds__(256) void ke2(float* __restrict__ ws){
  int b = blockIdx.x, t = threadIdx.x;
  int c = b >> 5, sh = b & 31;
  int nch = (c < 10) ? CPC : 1;
  int cb  = (c < 10) ? c*CPC : 520;
  float rden = 1.0f / ws[PS_OFF + (size_t)c*32 + sh];
  const float* part = ws + PART_OFF + (size_t)sh*256 + t;
  float a = 0.f;
  for (int k=0;k<nch;k++) a += part[(size_t)(cb+k)*8192];
  ws[XW_OFF + (size_t)c*8192 + (size_t)sh*256 + t] = a * rden;
}

// ---- KP: pooled per (c,s,eq), split-d over 4 thread groups. 176 blocks.
__global__ __launch_bounds__(256) void kp(float* __restrict__ ws,
    const float* __restrict__ Wv, const float* __restrict__ bv){
  int b = blockIdx.x; int c = b >> 4, rem = b & 15, s = rem >> 2, eq = rem & 3;
  int t = threadIdx.x, e64 = t & 63, dq = t >> 6;
  int e = eq*64 + e64, h = e >> 5;
  const float* xr = ws + XW_OFF + (size_t)c*8192 + (size_t)(s*8 + h)*256 + dq*64;
  const float* wv = Wv + (size_t)s*65536 + (size_t)(dq*64)*256 + e;
  float a = 0.f;
#pragma unroll 8
  for (int d=0; d<64; ++d) a = fmaf(wv[(size_t)d*256], xr[d], a);
  __shared__ float red[4][64];
  red[dq][e64] = a;
  __syncthreads();
  if (t < 64){
    float rcnt = (c < 10) ? (1.0f/(float)CS) : 0.125f;
    float p = (red[0][t]+red[1][t]+red[2][t]+red[3][t] + bv[s*256 + eq*64 + t]) * rcnt;
    ws[PL_OFF + (size_t)c*1024 + s*256 + eq*64 + t] = p;
  }
}

// ---- KO: out per (c,s,eq) = pooled @ Wo + bo. 176 blocks.
__global__ __launch_bounds__(256) void ko(float* __restrict__ ws,
    const float* __restrict__ Wo, const float* __restrict__ bo){
  int b = blockIdx.x; int c = b >> 4, rem = b & 15, s = rem >> 2, eq = rem & 3;
  int t = threadIdx.x, e64 = t & 63, dq = t >> 6;
  int e = eq*64 + e64;
  const float* pr = ws + PL_OFF + (size_t)c*1024 + s*256 + dq*64;
  const float* wo = Wo + (size_t)s*65536 + (size_t)(dq*64)*256 + e;
  float a = 0.f;
#pragma unroll 8
  for (int d=0; d<64; ++d) a = fmaf(wo[(size_t)d*256], pr[d], a);
  __shared__ float red[4][64];
  red[dq][e64] = a;
  __syncthreads();
  if (t < 64)
    ws[OL_OFF + (size_t)c*1024 + s*256 + eq*64 + t] =
      red[0][t]+red[1][t]+red[2][t]+red[3][t] + bo[s*256 + eq*64 + t];
}

// ---- KF1: h partials: block (c, fq, kq), f-slice 64, k-slice 256. 176 blocks.
__global__ __launch_bounds__(256) void kf1(const float* __restrict__ Wf1, float* __restrict__ ws){
  int b = blockIdx.x; int c = b >> 4, fq = (b >> 2) & 3, kq = b & 3;
  int t = threadIdx.x, f64 = t & 63, ks = t >> 6;
  const float* ol = ws + OL_OFF + (size_t)c*1024 + kq*256 + ks*64;
  const float* wf = Wf1 + (size_t)(kq*256 + ks*64)*256 + fq*64 + f64;
  float a = 0.f;
#pragma unroll 8
  for (int i=0; i<64; ++i) a = fmaf(wf[(size_t)i*256], ol[i], a);
  __shared__ float red[4][64];
  red[ks][f64] = a;
  __syncthreads();
  if (t < 64)
    ws[HP_OFF + (size_t)(c*4 + kq)*256 + fq*64 + t] = red[0][t]+red[1][t]+red[2][t]+red[3][t];
}

// ---- KLN: combine partials + bias -> LayerNorm -> GELU. 11 blocks.
__global__ __launch_bounds__(256) void kln(float* __restrict__ ws, const float* __restrict__ bf1,
    const float* __restrict__ lng, const float* __restrict__ lnb){
  int c = blockIdx.x, t = threadIdx.x;
  __shared__ float rs1[4], rs2[4];
  float hacc = bf1[t];
#pragma unroll
  for (int q=0;q<4;q++) hacc += ws[HP_OFF + (size_t)(c*4+q)*256 + t];
  float s1 = hacc, s2v = hacc*hacc;
  for (int off=32; off>0; off>>=1){ s1 += __shfl_down(s1, off, 64); s2v += __shfl_down(s2v, off, 64); }
  int wid = t>>6, lane = t&63;
  if (lane==0){ rs1[wid]=s1; rs2[wid]=s2v; }
  __syncthreads();
  float S1 = rs1[0]+rs1[1]+rs1[2]+rs1[3];
  float S2 = rs2[0]+rs2[1]+rs2[2]+rs2[3];
  float mu = S1*(1.0f/256.0f);
  float var = S2*(1.0f/256.0f) - mu*mu;
  float rsig = rsqrtf(var + 1e-5f);
  float hn = (hacc - mu)*rsig*lng[t] + lnb[t];
  float ge = 0.5f*hn*(1.0f + erff(hn*0.70710678118654752f));   // exact GELU
  ws[HL_OFF + (size_t)c*256 + t] = ge;
}

// ---- KF2: f2 partials: block (c, gq, kq), g-slice 64, k-slice 64. 176 blocks.
__global__ __launch_bounds__(256) void kf2(const float* __restrict__ Wf2, float* __restrict__ ws){
  int b = blockIdx.x; int c = b >> 4, gq = (b >> 2) & 3, kq = b & 3;
  int t = threadIdx.x, g64 = t & 63, ks = t >> 6;
  const float* hp = ws + HL_OFF + (size_t)c*256 + kq*64 + ks*16;
  const float* wf = Wf2 + (size_t)(kq*64 + ks*16)*256 + gq*64 + g64;
  float a = 0.f;
#pragma unroll
  for (int i=0; i<16; ++i) a = fmaf(wf[(size_t)i*256], hp[i], a);
  __shared__ float red[4][64];
  red[ks][g64] = a;
  __syncthreads();
  if (t < 64)
    ws[FP_OFF + (size_t)(c*4 + kq)*256 + gq*64 + t] = red[0][t]+red[1][t]+red[2][t]+red[3][t];
}

// ---- KBC2: sum Wf2 partials + bf2 once per block, broadcast to nodes. 8192 blocks.
__global__ __launch_bounds__(256) void kbc2(const float* __restrict__ ws, float4* __restrict__ out,
                                            const float* __restrict__ bf2){
  unsigned bidx = blockIdx.x, t = threadIdx.x;
  unsigned idx = bidx*256u + t;
  unsigned c = (bidx*4u) / (unsigned)CS;   // 3276 % 4 == 0 -> one cluster per block
  __shared__ float4 row[64];
  if (t < 64){
    const float4* FP4 = (const float4*)(ws + FP_OFF);
    float4 s0 = FP4[(c*4+0)*64 + t];
    float4 s1 = FP4[(c*4+1)*64 + t];
    float4 s2 = FP4[(c*4+2)*64 + t];
    float4 s3 = FP4[(c*4+3)*64 + t];
    float4 bb = ((const float4*)bf2)[t];
    row[t] = make_float4(s0.x+s1.x+s2.x+s3.x+bb.x, s0.y+s1.y+s2.y+s3.y+bb.y,
                         s0.z+s1.z+s2.z+s3.z+bb.z, s0.w+s1.w+s2.w+s3.w+bb.w);
  }
  __syncthreads();
  out[idx] = row[t & 63u];
}

extern "C" void kernel_launch(void* const* d_in, const int* in_sizes, int n_in,
                              void* d_out, int out_size, void* d_ws, size_t ws_size,
                              hipStream_t stream) {
  const float* x   = (const float*)d_in[0];
  // d_in[1] edge_index, d_in[2] batch: unused by the reference computation
  const float* Wk  = (const float*)d_in[3];
  const float* bk  = (const float*)d_in[4];
  const float* Wv  = (const float*)d_in[5];
  const float* bv  = (const float*)d_in[6];
  const float* Wo  = (const float*)d_in[7];
  const float* bo  = (const float*)d_in[8];
  const float* pq  = (const float*)d_in[9];
  const float* Wf1 = (const float*)d_in[10];
  const float* bf1 = (const float*)d_in[11];
  const float* lng = (const float*)d_in[12];
  const float* lnb = (const float*)d_in[13];
  const float* Wf2 = (const float*)d_in[14];
  const float* bf2 = (const float*)d_in[15];
  float* ws = (float*)d_ws;
  float4* out = (float4*)d_out;

  // zero the PS accumulators (atomic targets) — async, graph-capturable
  hipMemsetAsync((char*)d_ws + PS_OFF*sizeof(float), 0, 352*sizeof(float), stream);

  hipLaunchKernelGGL(ka,   dim3(33),   dim3(256), 0, stream, Wk, bk, pq, ws);
  hipLaunchKernelGGL(kbd4, dim3(NB),   dim3(512), 0, stream, x, ws);
  hipLaunchKernelGGL(ke2,  dim3(352),  dim3(256), 0, stream, ws);
  hipLaunchKernelGGL(kp,   dim3(176),  dim3(256), 0, stream, ws, Wv, bv);
  hipLaunchKernelGGL(ko,   dim3(176),  dim3(256), 0, stream, ws, Wo, bo);
  hipLaunchKernelGGL(kf1,  dim3(176),  dim3(256), 0, stream, Wf1, ws);
  hipLaunchKernelGGL(kln,  dim3(11),   dim3(256), 0, stream, ws, bf1, lng, lnb);
  hipLaunchKernelGGL(kf2,  dim3(176),  dim3(256), 0, stream, Wf2, ws);
  hipLaunchKernelGGL(kbc2, dim3(8192), dim3(256), 0, stream, ws, out, bf2);
}